// Round 1
// baseline (133.044 us; speedup 1.0000x reference)
//
#include <hip/hip_runtime.h>
#include <math.h>

// Problem constants (reference: B=1024, C=10, H=30, W=30)
constexpr int BATCH = 1024;
constexpr int NC    = 10;   // n_colors / channels
constexpr int HW    = 900;  // 30*30 pixels per image (divisible by 4)
constexpr int NQ    = 225;  // float4 quads per channel plane

union F4 { float4 v; float f[4]; };

// One block = one image. Thread t < 225 owns pixels [4t, 4t+3] via float4
// loads: 16 B/lane -> 1 KiB per wave-load instruction (coalescing sweet
// spot) instead of the previous 4 B/lane scalar loads.
// Phase A loads target+input (20 dwordx4 in flight), phase B loads pred.
// Each block writes ONE float4 partial {ce_sum, or_mask, packed_counts, 0}
// to ws[img] with a plain store -- no atomics, no memset needed.
//
// or_mask bits: 0-9 pred-color-present, 10-19 tgt-color-present,
//              20 any(pred!=tgt), 21 any(tgt!=inp), 22 any(pred!=inp)
// packed_counts: changed + (tchanged<<16)  (max 900 each, no overflow)
__global__ __launch_bounds__(256, 4) void loss_main(
    const float* __restrict__ pred, const float* __restrict__ target,
    const float* __restrict__ inp, float4* __restrict__ ws) {
  const int img = blockIdx.x;
  const int t   = threadIdx.x;

  float ce_sum = 0.f;
  unsigned combo = 0;
  int counts = 0;

  if (t < NQ) {
    const size_t base = (size_t)img * (NC * HW) + 4 * t;  // float offset

    // ---- phase A: target & input argmax (20 float4 loads issued) ----
    F4 tv[NC], gv[NC];
#pragma unroll
    for (int c = 0; c < NC; ++c)
      tv[c].v = *reinterpret_cast<const float4*>(target + base + c * HW);
#pragma unroll
    for (int c = 0; c < NC; ++c)
      gv[c].v = *reinterpret_cast<const float4*>(inp + base + c * HW);

    float tmax[4], gmax[4];
    int tidx[4], gidx[4];
#pragma unroll
    for (int k = 0; k < 4; ++k) {
      tmax[k] = tv[0].f[k]; tidx[k] = 0;
      gmax[k] = gv[0].f[k]; gidx[k] = 0;
    }
#pragma unroll
    for (int c = 1; c < NC; ++c) {
#pragma unroll
      for (int k = 0; k < 4; ++k) {
        // strict > keeps first index on ties (matches jnp.argmax)
        if (tv[c].f[k] > tmax[k]) { tmax[k] = tv[c].f[k]; tidx[k] = c; }
        if (gv[c].f[k] > gmax[k]) { gmax[k] = gv[c].f[k]; gidx[k] = c; }
      }
    }

    // ---- phase B: pred (10 float4 loads) ----
    F4 p[NC];
#pragma unroll
    for (int c = 0; c < NC; ++c)
      p[c].v = *reinterpret_cast<const float4*>(pred + base + c * HW);

    float pmax[4]; int pidx[4];
#pragma unroll
    for (int k = 0; k < 4; ++k) { pmax[k] = p[0].f[k]; pidx[k] = 0; }
#pragma unroll
    for (int c = 1; c < NC; ++c) {
#pragma unroll
      for (int k = 0; k < 4; ++k)
        if (p[c].f[k] > pmax[k]) { pmax[k] = p[c].f[k]; pidx[k] = c; }
    }

    // stable log-sum-exp: 10 independent exps per pixel
    float s[4] = {0.f, 0.f, 0.f, 0.f};
#pragma unroll
    for (int c = 0; c < NC; ++c) {
#pragma unroll
      for (int k = 0; k < 4; ++k)
        s[k] += __expf(p[c].f[k] - pmax[k]);
    }

    // pred value at target index (cndmask chain; tidx already known)
    float ptv[4];
#pragma unroll
    for (int k = 0; k < 4; ++k) ptv[k] = p[0].f[k];
#pragma unroll
    for (int c = 1; c < NC; ++c) {
#pragma unroll
      for (int k = 0; k < 4; ++k)
        if (tidx[k] == c) ptv[k] = p[c].f[k];
    }

#pragma unroll
    for (int k = 0; k < 4; ++k) {
      const float lse = pmax[k] + __logf(s[k]);
      const float ce  = lse - ptv[k];
      ce_sum += ce * ((pidx[k] != tidx[k]) ? 5.0f : 1.0f);  // 1 + 4*incorrect
      combo |= (1u << pidx[k]) | (1u << (10 + tidx[k]));
      if (pidx[k] != tidx[k]) combo |= 1u << 20;
      if (tidx[k] != gidx[k]) combo |= 1u << 21;
      if (pidx[k] != gidx[k]) combo |= 1u << 22;
      counts += ((pidx[k] != gidx[k]) ? 1 : 0) +
                ((tidx[k] != gidx[k]) ? (1 << 16) : 0);
    }
  }

  // ---- wave(64) reduction of 3 quantities ----
#pragma unroll
  for (int off = 32; off >= 1; off >>= 1) {
    ce_sum += __shfl_down(ce_sum, off);
    combo  |= __shfl_down(combo, off);
    counts += __shfl_down(counts, off);
  }

  __shared__ float s_ce[4];
  __shared__ unsigned s_or[4];
  __shared__ int s_cnt[4];
  const int wave = t >> 6;
  if ((t & 63) == 0) { s_ce[wave] = ce_sum; s_or[wave] = combo; s_cnt[wave] = counts; }
  __syncthreads();
  if (t == 0) {
    float4 slot;
    slot.x = s_ce[0] + s_ce[1] + s_ce[2] + s_ce[3];
    slot.y = __uint_as_float(s_or[0] | s_or[1] | s_or[2] | s_or[3]);
    slot.z = __int_as_float(s_cnt[0] + s_cnt[1] + s_cnt[2] + s_cnt[3]);
    slot.w = 0.f;
    ws[img] = slot;
  }
}

// Finalize: single block, 1024 threads, thread b = image b. Reads the one
// partial of its image, computes per-image terms, block-reduces the
// 5 global sums, thread 0 writes the 6 outputs.
__global__ __launch_bounds__(1024) void loss_final(
    const float4* __restrict__ ws, float* __restrict__ out) {
  const int b = threadIdx.x;

  const float4 v = ws[b];
  const float ce = v.x;
  const unsigned orv = __float_as_uint(v.y);
  const int cnt = __float_as_int(v.z);

  const int changed  = cnt & 0xFFFF;
  const int tchanged = cnt >> 16;
  const float exact   = (orv & (1u << 20)) ? 0.f : 1.f;     // all(pred==tgt)
  const float any_ti  = (orv & (1u << 21)) ? 1.f : 0.f;     // any(tgt!=inp)
  const float all_pi  = (orv & (1u << 22)) ? 0.f : 1.f;     // all(pred==inp)
  const unsigned pm = orv & 0x3FFu, tm = (orv >> 10) & 0x3FFu;
  const float d = (float)(changed - tchanged) * (1.0f / (float)HW);

  float r_ce   = ce;                 // sum of weighted CE
  float r_ex   = exact;              // exact-match count
  float r_cp   = any_ti * all_pi;    // copy-penalty count
  float r_td   = d * d;              // transform-diff sum
  float r_mi   = (float)__popc(tm & ~pm);  // missing colors

#pragma unroll
  for (int off = 32; off >= 1; off >>= 1) {
    r_ce += __shfl_down(r_ce, off);
    r_ex += __shfl_down(r_ex, off);
    r_cp += __shfl_down(r_cp, off);
    r_td += __shfl_down(r_td, off);
    r_mi += __shfl_down(r_mi, off);
  }

  __shared__ float red[16][5];
  const int wave = b >> 6;
  if ((b & 63) == 0) {
    red[wave][0] = r_ce; red[wave][1] = r_ex; red[wave][2] = r_cp;
    red[wave][3] = r_td; red[wave][4] = r_mi;
  }
  __syncthreads();
  if (b == 0) {
    float a0 = 0, a1 = 0, a2 = 0, a3 = 0, a4 = 0;
#pragma unroll
    for (int w = 0; w < 16; ++w) {
      a0 += red[w][0]; a1 += red[w][1]; a2 += red[w][2];
      a3 += red[w][3]; a4 += red[w][4];
    }
    const float ce_loss    = a0 * (1.0f / ((float)BATCH * (float)HW));
    const float exact_sum  = a1;
    const float exact_frac = exact_sum * (1.0f / (float)BATCH);
    const float copy_pen   = 5.0f * a2 * (1.0f / (float)BATCH);
    const float tdiff      = a3 * (1.0f / (float)BATCH);
    const float color_pen  = 0.1f * a4;
    float total = ce_loss - exact_frac + copy_pen + tdiff + color_pen;
    if (isnan(total)) total = 2.0f;
    else if (total > 100.0f) total = 10.0f;
    out[0] = total;
    out[1] = ce_loss;
    out[2] = copy_pen;
    out[3] = exact_frac;
    out[4] = exact_sum;
    out[5] = tdiff;
  }
}

extern "C" void kernel_launch(void* const* d_in, const int* in_sizes, int n_in,
                              void* d_out, int out_size, void* d_ws, size_t ws_size,
                              hipStream_t stream) {
  const float* pred   = (const float*)d_in[0];
  const float* target = (const float*)d_in[1];
  const float* inp    = (const float*)d_in[2];
  float4* ws = (float4*)d_ws;  // 1024 slots * 16 B = 16 KB; fully written
                               // every launch before being read -> no memset.
  loss_main<<<dim3(BATCH), dim3(256), 0, stream>>>(pred, target, inp, ws);
  loss_final<<<dim3(1), dim3(1024), 0, stream>>>(ws, (float*)d_out);
}